// Round 3
// baseline (569.076 us; speedup 1.0000x reference)
//
#include <hip/hip_runtime.h>
#include <math.h>

#define H   1024
#define V   50257
#define L   50
#define ENC 2048

// ws layout (floats). [0 .. 8448) zeroed by memset each launch; rest is
// fully overwritten before being read (no zeroing needed).
#define WS_U    0        // 1024  h @ W_h           (atomic, 16 partials)
#define WS_XR   1024     // 1024  combine raw       (atomic, 16 partials)
#define WS_GI   2048     // 3072  x @ wih           (atomic, 16 partials)
#define WS_GH   5120     // 3072  h @ whh           (atomic, 16 partials)
#define WS_ES   8192     // 1     sum exp(logits)   (atomic)
#define WS_ESM  8256     // 64    e-scores
#define WS_WSM  8320     // 64    softmax weights
#define WS_BAR  8384     // 16    grid-barrier counters (ints)
#define WS_ZERO_FLOATS 8448
#define WS_AA   8448     // 2048  attn_applied (plain stores, full coverage)
#define WS_SS   10496    // 32 * 51200  S-partial slabs (plain stores)

__device__ __forceinline__ void gridbar(int* bar, int slot, int nblk)
{
    __syncthreads();
    if (threadIdx.x == 0) {
        __hip_atomic_fetch_add(&bar[slot], 1, __ATOMIC_ACQ_REL,
                               __HIP_MEMORY_SCOPE_AGENT);
        while (__hip_atomic_load(&bar[slot], __ATOMIC_ACQUIRE,
                                 __HIP_MEMORY_SCOPE_AGENT) < nblk) {
            __builtin_amdgcn_s_sleep(1);
        }
    }
    __syncthreads();
}

// ---------------------------------------------------------------------------
// K_A (224 blocks x 256): phase1 u/S/gh matvecs; bar; phase2 e-scores (50
// blocks); bar; phase3 softmax (block 0); bar; phase4 attn_applied (8 blocks)
// S-partials: 32 disjoint slabs, plain float4 stores -> no atomic contention.
// ---------------------------------------------------------------------------
__global__ __launch_bounds__(256) void ka_attn(
    const float* __restrict__ W, const float* __restrict__ hid,
    const float* __restrict__ enc, const float* __restrict__ whh,
    const float* __restrict__ attn_b, const float* __restrict__ vW,
    const float* __restrict__ vb, float* __restrict__ ws,
    float* __restrict__ out)
{
    __shared__ float vec[10 * 64];
    __shared__ float red[4];
    const int tid = threadIdx.x;
    const int b = blockIdx.x;
    int* bar = (int*)(ws + WS_BAR);

    // ---------------- phase 1 ----------------
    if (b < 16) {                      // u: rows [b*64, b*64+64)
        const float4* W4 = (const float4*)W;     // row stride 256 float4
        if (tid < 64) vec[tid] = hid[b * 64 + tid];
        __syncthreads();
        float4 acc = {0.f, 0.f, 0.f, 0.f};
        const int rowbase = b * 64;
        #pragma unroll 4
        for (int ii = 0; ii < 64; ++ii) {
            float4 w = W4[(rowbase + ii) * 256 + tid];
            float s = vec[ii];
            acc.x = fmaf(s, w.x, acc.x); acc.y = fmaf(s, w.y, acc.y);
            acc.z = fmaf(s, w.z, acc.z); acc.w = fmaf(s, w.w, acc.w);
        }
        float* u = ws + WS_U;
        int j0 = tid * 4;
        atomicAdd(&u[j0 + 0], acc.x); atomicAdd(&u[j0 + 1], acc.y);
        atomicAdd(&u[j0 + 2], acc.z); atomicAdd(&u[j0 + 3], acc.w);
    } else if (b < 176) {              // S: slab stores, no atomics
        const float4* W4 = (const float4*)W;
        const int sb = b - 16;
        const int it = sb & 31;        // 32 i-tiles of 64 over ENC
        const int lt = sb >> 5;        // 5 l-tiles of 10
        for (int t = tid; t < 10 * 64; t += 256)
            vec[t] = enc[(lt * 10 + (t >> 6)) * ENC + it * 64 + (t & 63)];
        __syncthreads();
        float4 acc[10];
        #pragma unroll
        for (int l = 0; l < 10; ++l) acc[l] = make_float4(0.f, 0.f, 0.f, 0.f);
        const int rowbase = 1024 + it * 64;
        #pragma unroll 4
        for (int ii = 0; ii < 64; ++ii) {
            float4 w = W4[(rowbase + ii) * 256 + tid];
            #pragma unroll
            for (int l = 0; l < 10; ++l) {
                float s = vec[l * 64 + ii];
                acc[l].x = fmaf(s, w.x, acc[l].x); acc[l].y = fmaf(s, w.y, acc[l].y);
                acc[l].z = fmaf(s, w.z, acc[l].z); acc[l].w = fmaf(s, w.w, acc[l].w);
            }
        }
        float* slab = ws + WS_SS + (size_t)it * (L * H);
        #pragma unroll
        for (int l = 0; l < 10; ++l)
            ((float4*)(slab + (lt * 10 + l) * H))[tid] = acc[l];
    } else {                           // gh = h @ whh
        const int gb = b - 176;
        const int it = gb & 15;        // 16 i-tiles of 64 over H
        const int jt = gb >> 4;        // 3 j-tiles of 1024 cols
        const int rowbase = it * 64;
        if (tid < 64) vec[tid] = hid[rowbase + tid];
        __syncthreads();
        const float4* W4 = (const float4*)whh;   // row stride 768 float4
        float4 acc = {0.f, 0.f, 0.f, 0.f};
        const int col4 = jt * 256 + tid;
        #pragma unroll 4
        for (int ii = 0; ii < 64; ++ii) {
            float4 w = W4[(rowbase + ii) * 768 + col4];
            float s = vec[ii];
            acc.x = fmaf(s, w.x, acc.x); acc.y = fmaf(s, w.y, acc.y);
            acc.z = fmaf(s, w.z, acc.z); acc.w = fmaf(s, w.w, acc.w);
        }
        float* dst = ws + WS_GH;
        int j0 = jt * 1024 + tid * 4;
        atomicAdd(&dst[j0 + 0], acc.x); atomicAdd(&dst[j0 + 1], acc.y);
        atomicAdd(&dst[j0 + 2], acc.z); atomicAdd(&dst[j0 + 3], acc.w);
    }
    gridbar(bar, 0, 224);

    // ---------------- phase 2: e_l (blocks 0..49) ----------------
    if (b < L) {
        const float* u = ws + WS_U;
        float acc = 0.f;
        #pragma unroll
        for (int jj = 0; jj < 4; ++jj) {
            int j = jj * 256 + tid;
            float val = u[j] + attn_b[j];
            #pragma unroll 8
            for (int it = 0; it < 32; ++it)
                val += ws[WS_SS + (size_t)it * (L * H) + b * H + j];
            acc += fmaxf(val, 0.f) * vW[j];
        }
        #pragma unroll
        for (int off = 32; off; off >>= 1) acc += __shfl_down(acc, off);
        if ((tid & 63) == 0) red[tid >> 6] = acc;
        __syncthreads();
        if (tid == 0)
            ws[WS_ESM + b] = red[0] + red[1] + red[2] + red[3] + vb[0];
    }
    gridbar(bar, 1, 224);

    // ---------------- phase 3: softmax (block 0, wave 0) ----------------
    if (b == 0 && tid < 64) {
        float e = (tid < L) ? ws[WS_ESM + tid] : -1e30f;
        float m = e;
        #pragma unroll
        for (int off = 32; off; off >>= 1) m = fmaxf(m, __shfl_down(m, off));
        m = __shfl(m, 0);
        float ex = (tid < L) ? expf(e - m) : 0.f;
        float s = ex;
        #pragma unroll
        for (int off = 32; off; off >>= 1) s += __shfl_down(s, off);
        s = __shfl(s, 0);
        if (tid < L) {
            float w = ex / s;
            ws[WS_WSM + tid] = w;
            out[V + H + tid] = w;
        }
    }
    gridbar(bar, 2, 224);

    // ---------------- phase 4: attn_applied (blocks 0..7) ----------------
    if (b < 8) {
        if (tid < L) vec[tid] = ws[WS_WSM + tid];
        __syncthreads();
        const int col = b * 256 + tid;
        float a = 0.f;
        #pragma unroll 10
        for (int l = 0; l < L; ++l) a = fmaf(vec[l], enc[l * ENC + col], a);
        ws[WS_AA + col] = a;
    }
}

// ---------------------------------------------------------------------------
// K_B (48 blocks x 256): xr = [emb,aa] @ comb_W ; bar ; gi = relu(xr+cb) @ wih
// ---------------------------------------------------------------------------
__global__ __launch_bounds__(256) void kb_comb_gi(
    const float* __restrict__ combW, const float* __restrict__ emb,
    const int* __restrict__ idx, const float* __restrict__ wih,
    const float* __restrict__ comb_b, float* __restrict__ ws)
{
    __shared__ float vec[64];
    const int tid = threadIdx.x, b = blockIdx.x;
    int* bar = (int*)(ws + WS_BAR);

    {   // combine: rows [b*64, b*64+64) of comb_W (48 tiles over 3072)
        const int rowbase = b * 64;
        if (tid < 64) {
            int i = rowbase + tid;
            const float* embrow = emb + (size_t)idx[0] * H;
            vec[tid] = (i < H) ? embrow[i] : ws[WS_AA + (i - H)];
        }
        __syncthreads();
        const float4* W4 = (const float4*)combW;  // row stride 256 float4
        float4 acc = {0.f, 0.f, 0.f, 0.f};
        #pragma unroll 4
        for (int ii = 0; ii < 64; ++ii) {
            float4 w = W4[(rowbase + ii) * 256 + tid];
            float s = vec[ii];
            acc.x = fmaf(s, w.x, acc.x); acc.y = fmaf(s, w.y, acc.y);
            acc.z = fmaf(s, w.z, acc.z); acc.w = fmaf(s, w.w, acc.w);
        }
        float* xr = ws + WS_XR;
        int j0 = tid * 4;
        atomicAdd(&xr[j0 + 0], acc.x); atomicAdd(&xr[j0 + 1], acc.y);
        atomicAdd(&xr[j0 + 2], acc.z); atomicAdd(&xr[j0 + 3], acc.w);
    }
    gridbar(bar, 3, 48);
    {   // gi: 16 i-tiles x 3 j-tiles
        const int it = b & 15, jt = b >> 4;
        const int rowbase = it * 64;
        if (tid < 64) {
            int i = rowbase + tid;
            vec[tid] = fmaxf(ws[WS_XR + i] + comb_b[i], 0.f);
        }
        __syncthreads();
        const float4* W4 = (const float4*)wih;  // row stride 768 float4
        float4 acc = {0.f, 0.f, 0.f, 0.f};
        const int col4 = jt * 256 + tid;
        #pragma unroll 4
        for (int ii = 0; ii < 64; ++ii) {
            float4 w = W4[(rowbase + ii) * 768 + col4];
            float s = vec[ii];
            acc.x = fmaf(s, w.x, acc.x); acc.y = fmaf(s, w.y, acc.y);
            acc.z = fmaf(s, w.z, acc.z); acc.w = fmaf(s, w.w, acc.w);
        }
        float* dst = ws + WS_GI;
        int j0 = jt * 1024 + tid * 4;
        atomicAdd(&dst[j0 + 0], acc.x); atomicAdd(&dst[j0 + 1], acc.y);
        atomicAdd(&dst[j0 + 2], acc.z); atomicAdd(&dst[j0 + 3], acc.w);
    }
}

// ---------------------------------------------------------------------------
// K_C (786 x 512): every block computes h_new (GRU gates) from ws into LDS
// (block 0 also writes it to out[V..V+H)); then logits for its 64 vocab
// columns, 8 waves splitting the i-dim (unroll 8 -> 8 loads in flight/wave).
// ---------------------------------------------------------------------------
__global__ __launch_bounds__(512) void kc_logits(
    const float* __restrict__ outW, const float* __restrict__ outb,
    const float* __restrict__ bih, const float* __restrict__ bhh,
    const float* __restrict__ hid, float* out, float* __restrict__ ws)
{
    __shared__ float hn[H];
    __shared__ float part[8 * 64];
    const int tid = threadIdx.x;

    #pragma unroll
    for (int r = 0; r < 2; ++r) {
        const int k = tid + r * 512;
        float ir  = ws[WS_GI + k]        + bih[k];
        float iz  = ws[WS_GI + H + k]    + bih[H + k];
        float inn = ws[WS_GI + 2*H + k]  + bih[2*H + k];
        float hr  = ws[WS_GH + k]        + bhh[k];
        float hz  = ws[WS_GH + H + k]    + bhh[H + k];
        float hnn = ws[WS_GH + 2*H + k]  + bhh[2*H + k];
        float rg = 1.f / (1.f + expf(-(ir + hr)));
        float zg = 1.f / (1.f + expf(-(iz + hz)));
        float ng = tanhf(inn + rg * hnn);
        float hv = (1.f - zg) * ng + zg * hid[k];
        hn[k] = hv;
        if (blockIdx.x == 0) out[V + k] = hv;
    }
    __syncthreads();

    const int wave = tid >> 6, lane = tid & 63;
    const int v = blockIdx.x * 64 + lane;
    float a0 = 0.f, a1 = 0.f, a2 = 0.f, a3 = 0.f;
    float a4 = 0.f, a5 = 0.f, a6 = 0.f, a7 = 0.f;
    if (v < V) {
        const int ib = wave * 128;
        const float* p = outW + (size_t)ib * V + v;
        const size_t s = (size_t)V;
        #pragma unroll 4
        for (int i = 0; i < 128; i += 8) {
            float w0 = p[0],     w1 = p[s],     w2 = p[2 * s], w3 = p[3 * s];
            float w4 = p[4 * s], w5 = p[5 * s], w6 = p[6 * s], w7 = p[7 * s];
            a0 = fmaf(hn[ib + i],     w0, a0);
            a1 = fmaf(hn[ib + i + 1], w1, a1);
            a2 = fmaf(hn[ib + i + 2], w2, a2);
            a3 = fmaf(hn[ib + i + 3], w3, a3);
            a4 = fmaf(hn[ib + i + 4], w4, a4);
            a5 = fmaf(hn[ib + i + 5], w5, a5);
            a6 = fmaf(hn[ib + i + 6], w6, a6);
            a7 = fmaf(hn[ib + i + 7], w7, a7);
            p += 8 * s;
        }
    }
    part[wave * 64 + lane] = ((a0 + a1) + (a2 + a3)) + ((a4 + a5) + (a6 + a7));
    __syncthreads();

    if (wave == 0) {
        float sum = 0.f;
        #pragma unroll
        for (int w = 0; w < 8; ++w) sum += part[w * 64 + lane];
        float ex = 0.f;
        if (v < V) {
            float logit = sum + outb[v];
            out[v] = logit;
            ex = expf(logit);
        }
        #pragma unroll
        for (int off = 32; off; off >>= 1) ex += __shfl_down(ex, off);
        if (lane == 0) atomicAdd(&ws[WS_ES], ex);
    }
}

// ---------------------------------------------------------------------------
// K_D: out[v] -= log(sum exp)
// ---------------------------------------------------------------------------
__global__ __launch_bounds__(256) void kd_finalize(
    float* out, const float* __restrict__ ws)
{
    const int v = blockIdx.x * 256 + threadIdx.x;
    const float lse = logf(ws[WS_ES]);
    if (v < V) out[v] -= lse;
}

extern "C" void kernel_launch(void* const* d_in, const int* in_sizes, int n_in,
                              void* d_out, int out_size, void* d_ws, size_t ws_size,
                              hipStream_t stream)
{
    const int*   idx = (const int*)d_in[0];
    const float* hid = (const float*)d_in[1];
    const float* enc = (const float*)d_in[2];
    const float* emb = (const float*)d_in[3];
    const float* aW  = (const float*)d_in[4];
    const float* ab  = (const float*)d_in[5];
    const float* avW = (const float*)d_in[6];
    const float* avb = (const float*)d_in[7];
    const float* cW  = (const float*)d_in[8];
    const float* cb  = (const float*)d_in[9];
    const float* wih = (const float*)d_in[10];
    const float* bih = (const float*)d_in[11];
    const float* whh = (const float*)d_in[12];
    const float* bhh = (const float*)d_in[13];
    const float* oW  = (const float*)d_in[14];
    const float* ob  = (const float*)d_in[15];
    float* out = (float*)d_out;
    float* ws  = (float*)d_ws;

    hipMemsetAsync(ws, 0, WS_ZERO_FLOATS * 4, stream);
    ka_attn<<<224, 256, 0, stream>>>(aW, hid, enc, whh, ab, avW, avb, ws, out);
    kb_comb_gi<<<48, 256, 0, stream>>>(cW, emb, idx, wih, cb, ws);
    kc_logits<<<786, 512, 0, stream>>>(oW, ob, bih, bhh, hid, out, ws);
    kd_finalize<<<197, 256, 0, stream>>>(out, ws);
}